// Round 12
// baseline (348.491 us; speedup 1.0000x reference)
//
#include <hip/hip_runtime.h>
#include <math.h>

typedef __attribute__((ext_vector_type(8)))  short s16x8;   // 8 bf16 (4 VGPRs)
typedef __attribute__((ext_vector_type(16))) float f32x16;  // MFMA 32x32 acc
typedef __attribute__((ext_vector_type(2)))  float f32x2;

__device__ inline unsigned short f2bf(float f) {           // RNE f32 -> bf16
    unsigned u = __float_as_uint(f);
    u += 0x7fffu + ((u >> 16) & 1u);
    return (unsigned short)(u >> 16);
}
__device__ inline unsigned char f2fp8(float v) {           // f32 -> fp8 e4m3 (OCP on gfx950)
    return (unsigned char)(__builtin_amdgcn_cvt_pk_fp8_f32(v, v, 0, false) & 0xff);
}
// accumulate 8 fp8 channels (uint2) into f32 acc via HW cvt
__device__ inline void acc_fp8x8(float* a, uint2 v) {
    f32x2 p0 = __builtin_amdgcn_cvt_pk_f32_fp8(v.x, false);
    f32x2 p1 = __builtin_amdgcn_cvt_pk_f32_fp8(v.x, true);
    f32x2 p2 = __builtin_amdgcn_cvt_pk_f32_fp8(v.y, false);
    f32x2 p3 = __builtin_amdgcn_cvt_pk_f32_fp8(v.y, true);
    a[0] += p0.x; a[1] += p0.y; a[2] += p1.x; a[3] += p1.y;
    a[4] += p2.x; a[5] += p2.y; a[6] += p3.x; a[7] += p3.y;
}
// 8 fp8 -> 8 bf16 packed (EXACT: e4m3 values are representable in bf16)
__device__ inline uint4 fp8x8_to_bf16x8(uint2 v) {
    f32x2 p0 = __builtin_amdgcn_cvt_pk_f32_fp8(v.x, false);
    f32x2 p1 = __builtin_amdgcn_cvt_pk_f32_fp8(v.x, true);
    f32x2 p2 = __builtin_amdgcn_cvt_pk_f32_fp8(v.y, false);
    f32x2 p3 = __builtin_amdgcn_cvt_pk_f32_fp8(v.y, true);
    uint4 o;
    o.x = ((unsigned)f2bf(p0.y) << 16) | f2bf(p0.x);
    o.y = ((unsigned)f2bf(p1.y) << 16) | f2bf(p1.x);
    o.z = ((unsigned)f2bf(p2.y) << 16) | f2bf(p2.x);
    o.w = ((unsigned)f2bf(p3.y) << 16) | f2bf(p3.x);
    return o;
}

#define BMAX 3200   // max edges per producer chunk (LDS-resident)
#define RNG  512    // owner ranges (= producer count); per-range nodes <= 256
#define WPREP 262144 // total weight-permute elements
#define RCAP 4096   // fixed csr_src capacity per range (mean 3125, sd 56 -> >17 sd)

// ===========================================================================
// Merged prep + bucketize: blocks [0,RNG) bucketize; blocks >= RNG run prep.
// ===========================================================================
__global__ __launch_bounds__(256)
void prep_bucketize(const float* __restrict__ x, unsigned char* __restrict__ xq,
                    const float* __restrict__ W1a, unsigned short* __restrict__ Wf1a,
                    const float* __restrict__ W1b, unsigned short* __restrict__ Wf1b,
                    const float* __restrict__ W2a, unsigned short* __restrict__ Wf2a,
                    const float* __restrict__ W2b, unsigned short* __restrict__ Wf2b,
                    const float* __restrict__ W3a, unsigned short* __restrict__ Wf3a,
                    const float* __restrict__ W3b, unsigned short* __restrict__ Wf3b,
                    const int* __restrict__ src, const int* __restrict__ dst,
                    int2* __restrict__ pairs, int* __restrict__ offsg,
                    int N, int E, int C, int per) {
    __shared__ int sdst[BMAX];
    __shared__ int ssrc[BMAX];
    __shared__ int cnt[RNG];
    __shared__ int cur[RNG + 1];
    __shared__ int sh[256];
    const int t = threadIdx.x;

    if (blockIdx.x < RNG) {
        // ---------------- bucketize path ----------------
        const int p    = blockIdx.x;
        const int base = p * C;
        const int len  = min(C, E - base);

        cnt[t] = 0; cnt[t + 256] = 0;
        for (int i = t; i < len; i += 256) { sdst[i] = dst[base + i]; ssrc[i] = src[base + i]; }
        __syncthreads();
        for (int i = t; i < len; i += 256) {
            int r = sdst[i] / per;
            atomicAdd(&cnt[r], 1);
        }
        __syncthreads();
        const int cA = cnt[2 * t], cB = cnt[2 * t + 1];
        sh[t] = cA + cB;
        __syncthreads();
        for (int off = 1; off < 256; off <<= 1) {
            int add = (t >= off) ? sh[t - off] : 0;
            __syncthreads();
            sh[t] += add;
            __syncthreads();
        }
        const int excl = sh[t] - cA - cB;
        cur[2 * t] = excl;
        cur[2 * t + 1] = excl + cA;
        if (t == 255) cur[RNG] = sh[255];
        offsg[p * (RNG + 1) + 2 * t]     = excl;
        offsg[p * (RNG + 1) + 2 * t + 1] = excl + cA;
        if (t == 255) offsg[p * (RNG + 1) + RNG] = sh[255];
        __syncthreads();
        for (int i = t; i < len; i += 256) {
            int d = sdst[i];
            int r = d / per;
            int pos = atomicAdd(&cur[r], 1);
            pairs[base + pos] = make_int2(ssrc[i], d);
        }
        return;
    }

    // ---------------- prep path ----------------
    int i = (blockIdx.x - RNG) * 256 + t;
    int nx = N * 48;
    if (i < nx) { xq[i] = f2fp8(x[i]); return; }
    i -= nx;
    if (i < 24576) {   // Wf1a: K1=96, NS1=6
        int j = i & 7, lane = (i >> 3) & 63, pp = (i >> 9) & 1, sw = i >> 10;
        int s = sw % 6, w = sw / 6;
        int col = w * 64 + pp * 32 + (lane & 31);
        int k   = s * 16 + (lane >> 5) * 8 + j;
        Wf1a[i] = f2bf(W1a[(size_t)k * 256 + col]); return;
    }
    i -= 24576;
    if (i < 32768) {   // Wf1b: [256][128]
        int j = i & 7, lane = (i >> 3) & 63, sw = i >> 9;
        int s = sw & 15, w = sw >> 4;
        int col = w * 32 + (lane & 31);
        int k   = s * 16 + (lane >> 5) * 8 + j;
        Wf1b[i] = f2bf(W1b[(size_t)k * 128 + col]); return;
    }
    i -= 32768;
    if (i < 77824) {   // Wf2a: K1=304, NS1=19
        int j = i & 7, lane = (i >> 3) & 63, pp = (i >> 9) & 1, sw = i >> 10;
        int s = sw % 19, w = sw / 19;
        int col = w * 64 + pp * 32 + (lane & 31);
        int k   = s * 16 + (lane >> 5) * 8 + j;
        Wf2a[i] = f2bf(W2a[(size_t)k * 256 + col]); return;
    }
    i -= 77824;
    if (i < 32768) {   // Wf2b: [256][128]
        int j = i & 7, lane = (i >> 3) & 63, sw = i >> 9;
        int s = sw & 15, w = sw >> 4;
        int col = w * 32 + (lane & 31);
        int k   = s * 16 + (lane >> 5) * 8 + j;
        Wf2b[i] = f2bf(W2b[(size_t)k * 128 + col]); return;
    }
    i -= 32768;
    if (i < 77824) {   // Wf3a: K1=304, NS1=19
        int j = i & 7, lane = (i >> 3) & 63, pp = (i >> 9) & 1, sw = i >> 10;
        int s = sw % 19, w = sw / 19;
        int col = w * 64 + pp * 32 + (lane & 31);
        int k   = s * 16 + (lane >> 5) * 8 + j;
        Wf3a[i] = f2bf(W3a[(size_t)k * 256 + col]); return;
    }
    i -= 77824;
    if (i < 16384) {   // Wf3b: [256][40->64 pad], 2 wave-groups (ct)
        int j = i & 7, lane = (i >> 3) & 63, sw = i >> 9;
        int s = sw & 15, w = sw >> 4;      // w in {0,1}
        int col = w * 32 + (lane & 31);
        int k   = s * 16 + (lane >> 5) * 8 + j;
        float v = (col < 40) ? W3b[(size_t)k * 40 + col] : 0.f;
        Wf3b[i] = f2bf(v); return;
    }
}

// ===========================================================================
// place_all with FIXED per-range base rb = r*RCAP (round-12): rowptr needs no
// global compaction, so range_tot + prefix reduce are deleted entirely.
// ===========================================================================
__global__ __launch_bounds__(256)
void place_all(const int2* __restrict__ pairs, const int* __restrict__ offsg,
               int* __restrict__ rowptr, int* __restrict__ deg,
               int* __restrict__ csr_src, int N, int C, int per) {
    __shared__ int po[RNG];
    __shared__ int W[RNG + 1];
    __shared__ int sh[256];
    __shared__ int dcnt[256];
    __shared__ int curs[256];
    const int r  = blockIdx.x;
    const int lo = r * per;
    const int hi = min(lo + per, N);
    const int cnt = hi - lo;
    if (cnt <= 0) return;
    const int t = threadIdx.x;
    const int rb = r * RCAP;

    dcnt[t] = 0;
    const int pA = 2 * t, pB = 2 * t + 1;
    const int oA0 = offsg[pA * (RNG + 1) + r];
    const int oA1 = offsg[pA * (RNG + 1) + r + 1];
    const int oB0 = offsg[pB * (RNG + 1) + r];
    const int oB1 = offsg[pB * (RNG + 1) + r + 1];
    po[pA] = oA0; po[pB] = oB0;
    const int cA = oA1 - oA0, cB = oB1 - oB0;
    sh[t] = cA + cB;
    __syncthreads();
    for (int off = 1; off < 256; off <<= 1) {
        int add = (t >= off) ? sh[t - off] : 0;
        __syncthreads();
        sh[t] += add;
        __syncthreads();
    }
    const int excl = sh[t] - cA - cB;
    W[pA] = excl; W[pB] = excl + cA;
    if (t == 255) W[RNG] = sh[255];
    __syncthreads();
    const int tot = W[RNG];
    // pass 1: per-node counts
    for (int i = t; i < tot; i += 256) {
        int a = 0, b = RNG;
        while (b - a > 1) { int m = (a + b) >> 1; if (W[m] <= i) a = m; else b = m; }
        const int2 pr = pairs[(size_t)a * C + po[a] + (i - W[a])];
        atomicAdd(&dcnt[pr.y - lo], 1);
    }
    __syncthreads();
    // LDS exclusive scan of dcnt
    const int myc = dcnt[t];
    sh[t] = myc;
    __syncthreads();
    for (int off = 1; off < 256; off <<= 1) {
        int add = (t >= off) ? sh[t - off] : 0;
        __syncthreads();
        sh[t] += add;
        __syncthreads();
    }
    const int loc = sh[t] - myc;
    if (t < cnt) { rowptr[lo + t] = rb + loc; deg[lo + t] = myc; }
    curs[t] = rb + loc;
    __syncthreads();
    // pass 2: place (same pairs bytes, L2-hot)
    for (int i = t; i < tot; i += 256) {
        int a = 0, b = RNG;
        while (b - a > 1) { int m = (a + b) >> 1; if (W[m] <= i) a = m; else b = m; }
        const int2 pr = pairs[(size_t)a * C + po[a] + (i - W[a])];
        const int pos = atomicAdd(&curs[pr.y - lo], 1);   // LDS atomic
        if (pos < RNG * RCAP) csr_src[pos] = pr.x;
    }
}

// ===========================================================================
// LGConv gather from FP8 table. uint4 index loads + 8-edge unroll.
// ===========================================================================
template<int D, int LPN>
__global__ __launch_bounds__(256)
void lgconv_gather_fp8(const unsigned char* __restrict__ xq,
                       const int* __restrict__ rowptr,
                       const int* __restrict__ deg,
                       const int* __restrict__ csr_src,
                       unsigned short* __restrict__ out, int N) {
    const int g    = (blockIdx.x * 256 + threadIdx.x) / LPN;
    const int lane = threadIdx.x & (LPN - 1);
    if (g >= N) return;
    if (lane * 8 >= D) return;
    const int start = rowptr[g];
    const int dg    = deg[g];
    const unsigned char* xb = xq + lane * 8;
    float acc[8] = {0.f,0.f,0.f,0.f,0.f,0.f,0.f,0.f};
    int j = 0;
    for (; j + 7 < dg; j += 8) {
        const int4 ia = *(const int4*)(csr_src + start + j);
        const int4 ib = *(const int4*)(csr_src + start + j + 4);
        uint2 v0 = *(const uint2*)(xb + (size_t)ia.x * D);
        uint2 v1 = *(const uint2*)(xb + (size_t)ia.y * D);
        uint2 v2 = *(const uint2*)(xb + (size_t)ia.z * D);
        uint2 v3 = *(const uint2*)(xb + (size_t)ia.w * D);
        uint2 v4 = *(const uint2*)(xb + (size_t)ib.x * D);
        uint2 v5 = *(const uint2*)(xb + (size_t)ib.y * D);
        uint2 v6 = *(const uint2*)(xb + (size_t)ib.z * D);
        uint2 v7 = *(const uint2*)(xb + (size_t)ib.w * D);
        acc_fp8x8(acc, v0); acc_fp8x8(acc, v1);
        acc_fp8x8(acc, v2); acc_fp8x8(acc, v3);
        acc_fp8x8(acc, v4); acc_fp8x8(acc, v5);
        acc_fp8x8(acc, v6); acc_fp8x8(acc, v7);
    }
    if (j + 3 < dg) {
        const int4 ia = *(const int4*)(csr_src + start + j);
        uint2 v0 = *(const uint2*)(xb + (size_t)ia.x * D);
        uint2 v1 = *(const uint2*)(xb + (size_t)ia.y * D);
        uint2 v2 = *(const uint2*)(xb + (size_t)ia.z * D);
        uint2 v3 = *(const uint2*)(xb + (size_t)ia.w * D);
        acc_fp8x8(acc, v0); acc_fp8x8(acc, v1);
        acc_fp8x8(acc, v2); acc_fp8x8(acc, v3);
        j += 4;
    }
    for (; j < dg; ++j) {
        const int s0 = csr_src[start + j];
        uint2 v0 = *(const uint2*)(xb + (size_t)s0 * D);
        acc_fp8x8(acc, v0);
    }
    uint4 o;
    o.x = ((unsigned)f2bf(acc[1]) << 16) | f2bf(acc[0]);
    o.y = ((unsigned)f2bf(acc[3]) << 16) | f2bf(acc[2]);
    o.z = ((unsigned)f2bf(acc[5]) << 16) | f2bf(acc[4]);
    o.w = ((unsigned)f2bf(acc[7]) << 16) | f2bf(acc[6]);
    *(uint4*)(out + (size_t)g * D + lane * 8) = o;
}

// ===========================================================================
// Fused 2-layer MLP, bf16 MFMA (32x32x16), 32 rows/block, 4 waves.
// Round-12: (a) __launch_bounds__(256,2) gives the register allocator ~256
// VGPR budget (VGPR=36 forced ILP=1: one reg slot per weight fragment ->
// load s+1 waits on MFMA s); (b) K-loop split into EVEN/ODD accumulator
// chains (merged at the end) -- two independent load+MFMA streams the
// scheduler can interleave without register-reuse serialization.
// ===========================================================================
template<int LA, int LB, int LC, bool LSM>
__global__ __launch_bounds__(256, 2)
void fused_mlp_mfma(const unsigned short* __restrict__ segA,
                    const unsigned char* __restrict__ segB,
                    const unsigned char* __restrict__ segC,
                    const unsigned short* __restrict__ WfA, const float* __restrict__ ba,
                    const unsigned short* __restrict__ WfB, const float* __restrict__ bb,
                    void* __restrict__ outv, unsigned char* __restrict__ outq,
                    int n) {
    constexpr int K1   = LA + LB + LC;      // 96 or 304
    constexpr int NS1  = K1 / 16;
    constexpr int NCH  = K1 / 8;            // 16B chunks per row
    constexpr int KPAD = K1 + 8;            // 104 or 312 (16B-aligned rows)
    constexpr int K2P  = 264;               // hid row stride (bf16)
    constexpr int SW   = (32 * KPAD > 32 * K2P) ? 32 * KPAD : 32 * K2P;
    __shared__ __attribute__((aligned(16))) unsigned short smem[SW];
    unsigned short* Ab  = smem;             // stage-1 A tile   [32][KPAD]
    unsigned short* hid = smem;             // stage-1 out      [32][K2P] (union)

    const int tid  = threadIdx.x;
    const int wave = tid >> 6;
    const int lane = tid & 63;
    const int l31  = lane & 31;
    const int lh   = lane >> 5;
    const int row0 = blockIdx.x * 32;

    // ---- stage A tile: segA bf16 direct; segB/segC fp8 -> bf16 convert ----
    for (int c = tid; c < 32 * NCH; c += 256) {
        const int m  = c / NCH;
        const int kc = c - m * NCH;
        const int row = row0 + m;
        const int ra  = (row < n) ? row : (n - 1);
        uint4 val;
        if (kc * 8 < LA) {
            val = *(const uint4*)(segA + (size_t)ra * LA + kc * 8);
        } else {
            const unsigned char* qp;
            int koff;
            if (kc * 8 < LA + LB) { qp = segB + (size_t)ra * LB; koff = kc * 8 - LA; }
            else                  { qp = segC + (size_t)ra * LC; koff = kc * 8 - LA - LB; }
            val = fp8x8_to_bf16x8(*(const uint2*)(qp + koff));
        }
        *(uint4*)(Ab + m * KPAD + kc * 8) = val;
    }
    __syncthreads();

    // ---------------- stage 1: even/odd split-K chains ----------------
    f32x16 acc00a = {}, acc01a = {}, acc00b = {}, acc01b = {};
    const unsigned short* wfa = WfA + (size_t)wave * NS1 * 1024 + lane * 8;
    const int a0off = l31 * KPAD + lh * 8;

    #pragma unroll
    for (int s = 0; s < NS1; s += 2) {
        s16x8 a0 = *(const s16x8*)(Ab + a0off + s * 16);
        s16x8 b0 = *(const s16x8*)(wfa + s * 1024);
        s16x8 b1 = *(const s16x8*)(wfa + s * 1024 + 512);
        acc00a = __builtin_amdgcn_mfma_f32_32x32x16_bf16(a0, b0, acc00a, 0, 0, 0);
        acc01a = __builtin_amdgcn_mfma_f32_32x32x16_bf16(a0, b1, acc01a, 0, 0, 0);
        if (s + 1 < NS1) {
            s16x8 a1 = *(const s16x8*)(Ab + a0off + (s + 1) * 16);
            s16x8 c0 = *(const s16x8*)(wfa + (s + 1) * 1024);
            s16x8 c1 = *(const s16x8*)(wfa + (s + 1) * 1024 + 512);
            acc00b = __builtin_amdgcn_mfma_f32_32x32x16_bf16(a1, c0, acc00b, 0, 0, 0);
            acc01b = __builtin_amdgcn_mfma_f32_32x32x16_bf16(a1, c1, acc01b, 0, 0, 0);
        }
    }
    __syncthreads();                        // all A reads done before hid overwrites

    // epilogue: merge chains, + bias, relu -> hid[m][k] bf16
    {
        const int c0 = wave * 64 + l31;
        const int c1 = c0 + 32;
        const float bias0 = ba[c0];
        const float bias1 = ba[c1];
        #pragma unroll
        for (int t = 0; t < 16; ++t) {
            int rloc = (t & 3) + 8 * (t >> 2) + 4 * lh;
            hid[rloc * K2P + c0] = f2bf(fmaxf(acc00a[t] + acc00b[t] + bias0, 0.f));
            hid[rloc * K2P + c1] = f2bf(fmaxf(acc01a[t] + acc01b[t] + bias1, 0.f));
        }
    }
    __syncthreads();

    // ---------------- stage 2 ----------------
    if (!LSM) {
        f32x16 d0a = {}, d0b = {};
        const unsigned short* wfb = WfB + (size_t)wave * 16 * 512 + lane * 8;
        const int h0 = l31 * K2P + lh * 8;
        #pragma unroll
        for (int s = 0; s < 16; s += 2) {
            s16x8 a0 = *(const s16x8*)&hid[h0 + s * 16];
            s16x8 b  = *(const s16x8*)(wfb + s * 512);
            d0a = __builtin_amdgcn_mfma_f32_32x32x16_bf16(a0, b, d0a, 0, 0, 0);
            s16x8 a1 = *(const s16x8*)&hid[h0 + (s + 1) * 16];
            s16x8 c  = *(const s16x8*)(wfb + (s + 1) * 512);
            d0b = __builtin_amdgcn_mfma_f32_32x32x16_bf16(a1, c, d0b, 0, 0, 0);
        }
        const int col = wave * 32 + l31;
        const float bias = bb[col];
        #pragma unroll
        for (int t = 0; t < 16; ++t) {
            int rloc = (t & 3) + 8 * (t >> 2) + 4 * lh;
            int rr0 = row0 + rloc;
            if (rr0 < n)
                outq[(size_t)rr0 * 128 + col] = f2fp8(fmaxf(d0a[t] + d0b[t] + bias, 0.f));
        }
    } else {
        // waves 0,1 compute the 64 (padded) logit cols; waves 2,3 idle in MFMA
        float* lg = (float*)smem;           // [32][68] f32 = 8.7KB (after hid reads)
        f32x16 da = {}, db = {};
        if (wave < 2) {
            const unsigned short* wfb = WfB + (size_t)wave * 16 * 512 + lane * 8;
            const int h0 = l31 * K2P + lh * 8;
            #pragma unroll
            for (int s = 0; s < 16; s += 2) {
                s16x8 a = *(const s16x8*)&hid[h0 + s * 16];
                s16x8 b = *(const s16x8*)(wfb + s * 512);
                da = __builtin_amdgcn_mfma_f32_32x32x16_bf16(a, b, da, 0, 0, 0);
                s16x8 a1 = *(const s16x8*)&hid[h0 + (s + 1) * 16];
                s16x8 c  = *(const s16x8*)(wfb + (s + 1) * 512);
                db = __builtin_amdgcn_mfma_f32_32x32x16_bf16(a1, c, db, 0, 0, 0);
            }
        }
        __syncthreads();                    // done reading hid; reuse as logits
        if (wave < 2) {
            const int col = wave * 32 + l31;
            const float bias = (col < 40) ? bb[col] : 0.f;
            #pragma unroll
            for (int t = 0; t < 16; ++t) {
                int rloc = (t & 3) + 8 * (t >> 2) + 4 * lh;
                lg[rloc * 68 + col] = da[t] + db[t] + bias;
            }
        }
        __syncthreads();
        const int r = tid >> 3, j = tid & 7;   // 8 threads/row, 5 cols each
        float mx = -1e30f;
        #pragma unroll
        for (int c = 0; c < 5; ++c) mx = fmaxf(mx, lg[r * 68 + j * 5 + c]);
        mx = fmaxf(mx, __shfl_xor(mx, 1));
        mx = fmaxf(mx, __shfl_xor(mx, 2));
        mx = fmaxf(mx, __shfl_xor(mx, 4));
        float sm = 0.f;
        #pragma unroll
        for (int c = 0; c < 5; ++c) sm += __expf(lg[r * 68 + j * 5 + c] - mx);
        sm += __shfl_xor(sm, 1);
        sm += __shfl_xor(sm, 2);
        sm += __shfl_xor(sm, 4);
        const float lse = mx + __logf(sm);
        const int row = row0 + r;
        float* out = (float*)outv;
        if (row < n) {
            #pragma unroll
            for (int c = 0; c < 5; ++c)
                out[(size_t)row * 40 + j * 5 + c] = lg[r * 68 + j * 5 + c] - lse;
        }
    }
}

// ===========================================================================
extern "C" void kernel_launch(void* const* d_in, const int* in_sizes, int n_in,
                              void* d_out, int out_size, void* d_ws, size_t ws_size,
                              hipStream_t stream) {
    const float* x   = (const float*)d_in[0];
    const int*   ei  = (const int*)d_in[1];
    const float* W1a = (const float*)d_in[2];
    const float* b1a = (const float*)d_in[3];
    const float* W1b = (const float*)d_in[4];
    const float* b1b = (const float*)d_in[5];
    const float* W2a = (const float*)d_in[6];
    const float* b2a = (const float*)d_in[7];
    const float* W2b = (const float*)d_in[8];
    const float* b2b = (const float*)d_in[9];
    const float* W3a = (const float*)d_in[10];
    const float* b3a = (const float*)d_in[11];
    const float* W3b = (const float*)d_in[12];
    const float* b3b = (const float*)d_in[13];
    float* out = (float*)d_out;

    const int E = in_sizes[1] / 2;
    const int N = in_sizes[0] / 48;
    const int* src = ei;
    const int* dst = ei + E;

    const int nprod = RNG;                      // 512 producers == 512 owners
    const int C     = (E + nprod - 1) / nprod;  // 3125 for E=1.6M (<= BMAX)
    const int per   = (N + RNG - 1) / RNG;      // 196 nodes/owner (<= 256)

    // ---- workspace carve-up (256B aligned) ----
    char* p = (char*)d_ws;
    auto alloc = [&](size_t bytes) { void* q = p; p += (bytes + 255) & ~(size_t)255; return q; };
    unsigned char*  xq   = (unsigned char*) alloc((size_t)N * 48);
    unsigned short* c1   = (unsigned short*)alloc((size_t)N * 48  * 2);
    unsigned char*  h1q  = (unsigned char*) alloc((size_t)N * 128);
    unsigned short* c2   = (unsigned short*)alloc((size_t)N * 128 * 2);  // also c3
    unsigned char*  h2q  = (unsigned char*) alloc((size_t)N * 128);
    unsigned short* Wf1a = (unsigned short*)alloc((size_t)24576 * 2);
    unsigned short* Wf1b = (unsigned short*)alloc((size_t)32768 * 2);
    unsigned short* Wf2a = (unsigned short*)alloc((size_t)77824 * 2);
    unsigned short* Wf2b = (unsigned short*)alloc((size_t)32768 * 2);
    unsigned short* Wf3a = (unsigned short*)alloc((size_t)77824 * 2);
    unsigned short* Wf3b = (unsigned short*)alloc((size_t)16384 * 2);
    int* deg     = (int*)alloc((size_t)N * 4);
    int* rowptr  = (int*)alloc((size_t)N * 4);
    int* csr_src = (int*)alloc((size_t)RNG * RCAP * 4);
    int2* pairs  = (int2*)alloc((size_t)nprod * C * 8);
    int* offsg   = (int*)alloc((size_t)nprod * (RNG + 1) * 4);

    const int nblk32 = (N + 31) / 32;

    // ---- merged prep + bucketize ----
    {
        int prep_total = N * 48 + WPREP;
        int nblk = RNG + (prep_total + 255) / 256;
        prep_bucketize<<<nblk, 256, 0, stream>>>(
            x, xq, W1a, Wf1a, W1b, Wf1b, W2a, Wf2a, W2b, Wf2b,
            W3a, Wf3a, W3b, Wf3b, src, dst, pairs, offsg, N, E, C, per);
    }
    place_all<<<RNG, 256, 0, stream>>>(pairs, offsg, rowptr, deg, csr_src,
                                       N, C, per);

    // ---- layer 1 ----
    lgconv_gather_fp8<48, 8><<<((size_t)N * 8 + 255) / 256, 256, 0, stream>>>(
        xq, rowptr, deg, csr_src, c1, N);
    fused_mlp_mfma<48, 48, 0, false><<<nblk32, 256, 0, stream>>>(
        c1, xq, (const unsigned char*)nullptr, Wf1a, b1a, Wf1b, b1b,
        nullptr, h1q, N);

    // ---- layer 2 ----
    lgconv_gather_fp8<128, 16><<<((size_t)N * 16 + 255) / 256, 256, 0, stream>>>(
        h1q, rowptr, deg, csr_src, c2, N);
    fused_mlp_mfma<128, 128, 48, false><<<nblk32, 256, 0, stream>>>(
        c2, h1q, xq, Wf2a, b2a, Wf2b, b2b, nullptr, h2q, N);

    // ---- layer 3 ----
    lgconv_gather_fp8<128, 16><<<((size_t)N * 16 + 255) / 256, 256, 0, stream>>>(
        h2q, rowptr, deg, csr_src, c2, N);   // c3 reuses c2 slot
    fused_mlp_mfma<128, 128, 48, true><<<nblk32, 256, 0, stream>>>(
        c2, h2q, xq, Wf3a, b3a, Wf3b, b3b, out, (unsigned char*)nullptr, N);
}

// Round 13
// 331.918 us; speedup vs baseline: 1.0499x; 1.0499x over previous
//
#include <hip/hip_runtime.h>
#include <math.h>

typedef __attribute__((ext_vector_type(8)))  short s16x8;   // 8 bf16 (4 VGPRs)
typedef __attribute__((ext_vector_type(16))) float f32x16;  // MFMA 32x32 acc
typedef __attribute__((ext_vector_type(2)))  float f32x2;

__device__ inline unsigned short f2bf(float f) {           // RNE f32 -> bf16
    unsigned u = __float_as_uint(f);
    u += 0x7fffu + ((u >> 16) & 1u);
    return (unsigned short)(u >> 16);
}
__device__ inline unsigned char f2fp8(float v) {           // f32 -> fp8 e4m3 (OCP on gfx950)
    return (unsigned char)(__builtin_amdgcn_cvt_pk_fp8_f32(v, v, 0, false) & 0xff);
}
// accumulate 8 fp8 channels (uint2) into f32 acc via HW cvt
__device__ inline void acc_fp8x8(float* a, uint2 v) {
    f32x2 p0 = __builtin_amdgcn_cvt_pk_f32_fp8(v.x, false);
    f32x2 p1 = __builtin_amdgcn_cvt_pk_f32_fp8(v.x, true);
    f32x2 p2 = __builtin_amdgcn_cvt_pk_f32_fp8(v.y, false);
    f32x2 p3 = __builtin_amdgcn_cvt_pk_f32_fp8(v.y, true);
    a[0] += p0.x; a[1] += p0.y; a[2] += p1.x; a[3] += p1.y;
    a[4] += p2.x; a[5] += p2.y; a[6] += p3.x; a[7] += p3.y;
}
__device__ inline void acc_fp8x16(float* a, uint4 v) {
    acc_fp8x8(a,     make_uint2(v.x, v.y));
    acc_fp8x8(a + 8, make_uint2(v.z, v.w));
}
// 8 fp8 -> 8 bf16 packed (EXACT: e4m3 values are representable in bf16)
__device__ inline uint4 fp8x8_to_bf16x8(uint2 v) {
    f32x2 p0 = __builtin_amdgcn_cvt_pk_f32_fp8(v.x, false);
    f32x2 p1 = __builtin_amdgcn_cvt_pk_f32_fp8(v.x, true);
    f32x2 p2 = __builtin_amdgcn_cvt_pk_f32_fp8(v.y, false);
    f32x2 p3 = __builtin_amdgcn_cvt_pk_f32_fp8(v.y, true);
    uint4 o;
    o.x = ((unsigned)f2bf(p0.y) << 16) | f2bf(p0.x);
    o.y = ((unsigned)f2bf(p1.y) << 16) | f2bf(p1.x);
    o.z = ((unsigned)f2bf(p2.y) << 16) | f2bf(p2.x);
    o.w = ((unsigned)f2bf(p3.y) << 16) | f2bf(p3.x);
    return o;
}
__device__ inline uint4 pack_bf16x8(const float* a) {
    uint4 o;
    o.x = ((unsigned)f2bf(a[1]) << 16) | f2bf(a[0]);
    o.y = ((unsigned)f2bf(a[3]) << 16) | f2bf(a[2]);
    o.z = ((unsigned)f2bf(a[5]) << 16) | f2bf(a[4]);
    o.w = ((unsigned)f2bf(a[7]) << 16) | f2bf(a[6]);
    return o;
}

#define BMAX 3200   // max edges per producer chunk (LDS-resident)
#define RNG  512    // owner ranges (= producer count); per-range nodes <= 256
#define WPREP 262144 // total weight-permute elements
#define RCAP 4096   // fixed csr_src capacity per range (mean 3125, sd 56 -> >17 sd)

// ===========================================================================
// Merged prep + bucketize: blocks [0,RNG) bucketize; blocks >= RNG run prep.
// ===========================================================================
__global__ __launch_bounds__(256)
void prep_bucketize(const float* __restrict__ x, unsigned char* __restrict__ xq,
                    const float* __restrict__ W1a, unsigned short* __restrict__ Wf1a,
                    const float* __restrict__ W1b, unsigned short* __restrict__ Wf1b,
                    const float* __restrict__ W2a, unsigned short* __restrict__ Wf2a,
                    const float* __restrict__ W2b, unsigned short* __restrict__ Wf2b,
                    const float* __restrict__ W3a, unsigned short* __restrict__ Wf3a,
                    const float* __restrict__ W3b, unsigned short* __restrict__ Wf3b,
                    const int* __restrict__ src, const int* __restrict__ dst,
                    int2* __restrict__ pairs, int* __restrict__ offsg,
                    int N, int E, int C, int per) {
    __shared__ int sdst[BMAX];
    __shared__ int ssrc[BMAX];
    __shared__ int cnt[RNG];
    __shared__ int cur[RNG + 1];
    __shared__ int sh[256];
    const int t = threadIdx.x;

    if (blockIdx.x < RNG) {
        // ---------------- bucketize path ----------------
        const int p    = blockIdx.x;
        const int base = p * C;
        const int len  = min(C, E - base);

        cnt[t] = 0; cnt[t + 256] = 0;
        for (int i = t; i < len; i += 256) { sdst[i] = dst[base + i]; ssrc[i] = src[base + i]; }
        __syncthreads();
        for (int i = t; i < len; i += 256) {
            int r = sdst[i] / per;
            atomicAdd(&cnt[r], 1);
        }
        __syncthreads();
        const int cA = cnt[2 * t], cB = cnt[2 * t + 1];
        sh[t] = cA + cB;
        __syncthreads();
        for (int off = 1; off < 256; off <<= 1) {
            int add = (t >= off) ? sh[t - off] : 0;
            __syncthreads();
            sh[t] += add;
            __syncthreads();
        }
        const int excl = sh[t] - cA - cB;
        cur[2 * t] = excl;
        cur[2 * t + 1] = excl + cA;
        if (t == 255) cur[RNG] = sh[255];
        offsg[p * (RNG + 1) + 2 * t]     = excl;
        offsg[p * (RNG + 1) + 2 * t + 1] = excl + cA;
        if (t == 255) offsg[p * (RNG + 1) + RNG] = sh[255];
        __syncthreads();
        for (int i = t; i < len; i += 256) {
            int d = sdst[i];
            int r = d / per;
            int pos = atomicAdd(&cur[r], 1);
            pairs[base + pos] = make_int2(ssrc[i], d);
        }
        return;
    }

    // ---------------- prep path ----------------
    int i = (blockIdx.x - RNG) * 256 + t;
    int nx = N * 48;
    if (i < nx) { xq[i] = f2fp8(x[i]); return; }
    i -= nx;
    if (i < 24576) {   // Wf1a: K1=96, NS1=6
        int j = i & 7, lane = (i >> 3) & 63, pp = (i >> 9) & 1, sw = i >> 10;
        int s = sw % 6, w = sw / 6;
        int col = w * 64 + pp * 32 + (lane & 31);
        int k   = s * 16 + (lane >> 5) * 8 + j;
        Wf1a[i] = f2bf(W1a[(size_t)k * 256 + col]); return;
    }
    i -= 24576;
    if (i < 32768) {   // Wf1b: [256][128]
        int j = i & 7, lane = (i >> 3) & 63, sw = i >> 9;
        int s = sw & 15, w = sw >> 4;
        int col = w * 32 + (lane & 31);
        int k   = s * 16 + (lane >> 5) * 8 + j;
        Wf1b[i] = f2bf(W1b[(size_t)k * 128 + col]); return;
    }
    i -= 32768;
    if (i < 77824) {   // Wf2a: K1=304, NS1=19
        int j = i & 7, lane = (i >> 3) & 63, pp = (i >> 9) & 1, sw = i >> 10;
        int s = sw % 19, w = sw / 19;
        int col = w * 64 + pp * 32 + (lane & 31);
        int k   = s * 16 + (lane >> 5) * 8 + j;
        Wf2a[i] = f2bf(W2a[(size_t)k * 256 + col]); return;
    }
    i -= 77824;
    if (i < 32768) {   // Wf2b: [256][128]
        int j = i & 7, lane = (i >> 3) & 63, sw = i >> 9;
        int s = sw & 15, w = sw >> 4;
        int col = w * 32 + (lane & 31);
        int k   = s * 16 + (lane >> 5) * 8 + j;
        Wf2b[i] = f2bf(W2b[(size_t)k * 128 + col]); return;
    }
    i -= 32768;
    if (i < 77824) {   // Wf3a: K1=304, NS1=19
        int j = i & 7, lane = (i >> 3) & 63, pp = (i >> 9) & 1, sw = i >> 10;
        int s = sw % 19, w = sw / 19;
        int col = w * 64 + pp * 32 + (lane & 31);
        int k   = s * 16 + (lane >> 5) * 8 + j;
        Wf3a[i] = f2bf(W3a[(size_t)k * 256 + col]); return;
    }
    i -= 77824;
    if (i < 16384) {   // Wf3b: [256][40->64 pad], 2 wave-groups (ct)
        int j = i & 7, lane = (i >> 3) & 63, sw = i >> 9;
        int s = sw & 15, w = sw >> 4;      // w in {0,1}
        int col = w * 32 + (lane & 31);
        int k   = s * 16 + (lane >> 5) * 8 + j;
        float v = (col < 40) ? W3b[(size_t)k * 40 + col] : 0.f;
        Wf3b[i] = f2bf(v); return;
    }
}

// ===========================================================================
// place_all with FIXED per-range base rb = r*RCAP (kept from round-12; not
// implicated in the regression; removes range_tot + prefix).
// ===========================================================================
__global__ __launch_bounds__(256)
void place_all(const int2* __restrict__ pairs, const int* __restrict__ offsg,
               int* __restrict__ rowptr, int* __restrict__ deg,
               int* __restrict__ csr_src, int N, int C, int per) {
    __shared__ int po[RNG];
    __shared__ int W[RNG + 1];
    __shared__ int sh[256];
    __shared__ int dcnt[256];
    __shared__ int curs[256];
    const int r  = blockIdx.x;
    const int lo = r * per;
    const int hi = min(lo + per, N);
    const int cnt = hi - lo;
    if (cnt <= 0) return;
    const int t = threadIdx.x;
    const int rb = r * RCAP;

    dcnt[t] = 0;
    const int pA = 2 * t, pB = 2 * t + 1;
    const int oA0 = offsg[pA * (RNG + 1) + r];
    const int oA1 = offsg[pA * (RNG + 1) + r + 1];
    const int oB0 = offsg[pB * (RNG + 1) + r];
    const int oB1 = offsg[pB * (RNG + 1) + r + 1];
    po[pA] = oA0; po[pB] = oB0;
    const int cA = oA1 - oA0, cB = oB1 - oB0;
    sh[t] = cA + cB;
    __syncthreads();
    for (int off = 1; off < 256; off <<= 1) {
        int add = (t >= off) ? sh[t - off] : 0;
        __syncthreads();
        sh[t] += add;
        __syncthreads();
    }
    const int excl = sh[t] - cA - cB;
    W[pA] = excl; W[pB] = excl + cA;
    if (t == 255) W[RNG] = sh[255];
    __syncthreads();
    const int tot = W[RNG];
    // pass 1: per-node counts
    for (int i = t; i < tot; i += 256) {
        int a = 0, b = RNG;
        while (b - a > 1) { int m = (a + b) >> 1; if (W[m] <= i) a = m; else b = m; }
        const int2 pr = pairs[(size_t)a * C + po[a] + (i - W[a])];
        atomicAdd(&dcnt[pr.y - lo], 1);
    }
    __syncthreads();
    // LDS exclusive scan of dcnt
    const int myc = dcnt[t];
    sh[t] = myc;
    __syncthreads();
    for (int off = 1; off < 256; off <<= 1) {
        int add = (t >= off) ? sh[t - off] : 0;
        __syncthreads();
        sh[t] += add;
        __syncthreads();
    }
    const int loc = sh[t] - myc;
    if (t < cnt) { rowptr[lo + t] = rb + loc; deg[lo + t] = myc; }
    curs[t] = rb + loc;
    __syncthreads();
    // pass 2: place (same pairs bytes, L2-hot)
    for (int i = t; i < tot; i += 256) {
        int a = 0, b = RNG;
        while (b - a > 1) { int m = (a + b) >> 1; if (W[m] <= i) a = m; else b = m; }
        const int2 pr = pairs[(size_t)a * C + po[a] + (i - W[a])];
        const int pos = atomicAdd(&curs[pr.y - lo], 1);   // LDS atomic
        if (pos < RNG * RCAP) csr_src[pos] = pr.x;
    }
}

// ===========================================================================
// LGConv gather from FP8 table. Round-13: CPL channels/lane (16 for D=128 ->
// one 16B uint4 load/row/lane instead of two 8B; halves VMEM issue count).
// int4 index loads, 4-edge unroll.
// ===========================================================================
template<int D, int LPN, int CPL>
__global__ __launch_bounds__(256)
void lgconv_gather_fp8(const unsigned char* __restrict__ xq,
                       const int* __restrict__ rowptr,
                       const int* __restrict__ deg,
                       const int* __restrict__ csr_src,
                       unsigned short* __restrict__ out, int N) {
    const int g    = (blockIdx.x * 256 + threadIdx.x) / LPN;
    const int lane = threadIdx.x & (LPN - 1);
    if (g >= N) return;
    if (lane * CPL >= D) return;
    const int start = rowptr[g];
    const int dg    = deg[g];
    const unsigned char* xb = xq + lane * CPL;
    float acc[CPL];
    #pragma unroll
    for (int k = 0; k < CPL; ++k) acc[k] = 0.f;
    int j = 0;
    if constexpr (CPL == 16) {
        for (; j + 3 < dg; j += 4) {
            const int4 ia = *(const int4*)(csr_src + start + j);
            uint4 v0 = *(const uint4*)(xb + (size_t)ia.x * D);
            uint4 v1 = *(const uint4*)(xb + (size_t)ia.y * D);
            uint4 v2 = *(const uint4*)(xb + (size_t)ia.z * D);
            uint4 v3 = *(const uint4*)(xb + (size_t)ia.w * D);
            acc_fp8x16(acc, v0); acc_fp8x16(acc, v1);
            acc_fp8x16(acc, v2); acc_fp8x16(acc, v3);
        }
        for (; j < dg; ++j) {
            const int s0 = csr_src[start + j];
            uint4 v0 = *(const uint4*)(xb + (size_t)s0 * D);
            acc_fp8x16(acc, v0);
        }
        uint4 o0 = pack_bf16x8(acc);
        uint4 o1 = pack_bf16x8(acc + 8);
        unsigned short* op = out + (size_t)g * D + lane * CPL;
        *(uint4*)op = o0;
        *(uint4*)(op + 8) = o1;
    } else {
        for (; j + 7 < dg; j += 8) {
            const int4 ia = *(const int4*)(csr_src + start + j);
            const int4 ib = *(const int4*)(csr_src + start + j + 4);
            uint2 v0 = *(const uint2*)(xb + (size_t)ia.x * D);
            uint2 v1 = *(const uint2*)(xb + (size_t)ia.y * D);
            uint2 v2 = *(const uint2*)(xb + (size_t)ia.z * D);
            uint2 v3 = *(const uint2*)(xb + (size_t)ia.w * D);
            uint2 v4 = *(const uint2*)(xb + (size_t)ib.x * D);
            uint2 v5 = *(const uint2*)(xb + (size_t)ib.y * D);
            uint2 v6 = *(const uint2*)(xb + (size_t)ib.z * D);
            uint2 v7 = *(const uint2*)(xb + (size_t)ib.w * D);
            acc_fp8x8(acc, v0); acc_fp8x8(acc, v1);
            acc_fp8x8(acc, v2); acc_fp8x8(acc, v3);
            acc_fp8x8(acc, v4); acc_fp8x8(acc, v5);
            acc_fp8x8(acc, v6); acc_fp8x8(acc, v7);
        }
        if (j + 3 < dg) {
            const int4 ia = *(const int4*)(csr_src + start + j);
            uint2 v0 = *(const uint2*)(xb + (size_t)ia.x * D);
            uint2 v1 = *(const uint2*)(xb + (size_t)ia.y * D);
            uint2 v2 = *(const uint2*)(xb + (size_t)ia.z * D);
            uint2 v3 = *(const uint2*)(xb + (size_t)ia.w * D);
            acc_fp8x8(acc, v0); acc_fp8x8(acc, v1);
            acc_fp8x8(acc, v2); acc_fp8x8(acc, v3);
            j += 4;
        }
        for (; j < dg; ++j) {
            const int s0 = csr_src[start + j];
            uint2 v0 = *(const uint2*)(xb + (size_t)s0 * D);
            acc_fp8x8(acc, v0);
        }
        uint4 o = pack_bf16x8(acc);
        *(uint4*)(out + (size_t)g * D + lane * CPL) = o;
    }
}

// ===========================================================================
// Fused 2-layer MLP, bf16 MFMA (32x32x16), 32 rows/block, 4 waves.
// EXACT round-11 form (fp8 inputs, fp8 h-output, fragment-major weights,
// in-loop weight loads, single accumulator chains). Rounds 5-12 proved this
// ~41us schedule is the floor for this structure: occupancy up/down, hoist,
// ring, split-K + launch_bounds all tied or regressed. DO NOT TOUCH.
// ===========================================================================
template<int LA, int LB, int LC, bool LSM>
__global__ __launch_bounds__(256)
void fused_mlp_mfma(const unsigned short* __restrict__ segA,
                    const unsigned char* __restrict__ segB,
                    const unsigned char* __restrict__ segC,
                    const unsigned short* __restrict__ WfA, const float* __restrict__ ba,
                    const unsigned short* __restrict__ WfB, const float* __restrict__ bb,
                    void* __restrict__ outv, unsigned char* __restrict__ outq,
                    int n) {
    constexpr int K1   = LA + LB + LC;      // 96 or 304
    constexpr int NS1  = K1 / 16;
    constexpr int NCH  = K1 / 8;            // 16B chunks per row
    constexpr int KPAD = K1 + 8;            // 104 or 312 (16B-aligned rows)
    constexpr int K2P  = 264;               // hid row stride (bf16)
    constexpr int SW   = (32 * KPAD > 32 * K2P) ? 32 * KPAD : 32 * K2P;
    __shared__ __attribute__((aligned(16))) unsigned short smem[SW];
    unsigned short* Ab  = smem;             // stage-1 A tile   [32][KPAD]
    unsigned short* hid = smem;             // stage-1 out      [32][K2P] (union)

    const int tid  = threadIdx.x;
    const int wave = tid >> 6;
    const int lane = tid & 63;
    const int l31  = lane & 31;
    const int lh   = lane >> 5;
    const int row0 = blockIdx.x * 32;

    // ---- stage A tile: segA bf16 direct; segB/segC fp8 -> bf16 convert ----
    for (int c = tid; c < 32 * NCH; c += 256) {
        const int m  = c / NCH;
        const int kc = c - m * NCH;
        const int row = row0 + m;
        const int ra  = (row < n) ? row : (n - 1);
        uint4 val;
        if (kc * 8 < LA) {
            val = *(const uint4*)(segA + (size_t)ra * LA + kc * 8);
        } else {
            const unsigned char* qp;
            int koff;
            if (kc * 8 < LA + LB) { qp = segB + (size_t)ra * LB; koff = kc * 8 - LA; }
            else                  { qp = segC + (size_t)ra * LC; koff = kc * 8 - LA - LB; }
            val = fp8x8_to_bf16x8(*(const uint2*)(qp + koff));
        }
        *(uint4*)(Ab + m * KPAD + kc * 8) = val;
    }
    __syncthreads();

    // ---------------- stage 1: rows 0-31, 64 cols/wave ----------------
    f32x16 acc00 = {}, acc01 = {};
    const unsigned short* wfa = WfA + (size_t)wave * NS1 * 1024 + lane * 8;
    const int a0off = l31 * KPAD + lh * 8;

    #pragma unroll
    for (int s = 0; s < NS1; ++s) {
        s16x8 a0 = *(const s16x8*)(Ab + a0off + s * 16);
        s16x8 b0 = *(const s16x8*)(wfa + s * 1024);
        s16x8 b1 = *(const s16x8*)(wfa + s * 1024 + 512);
        acc00 = __builtin_amdgcn_mfma_f32_32x32x16_bf16(a0, b0, acc00, 0, 0, 0);
        acc01 = __builtin_amdgcn_mfma_f32_32x32x16_bf16(a0, b1, acc01, 0, 0, 0);
    }
    __syncthreads();                        // all A reads done before hid overwrites

    // epilogue: + bias, relu -> hid[m][k] bf16 (C/D layout, m74/m101)
    {
        const int c0 = wave * 64 + l31;
        const int c1 = c0 + 32;
        const float bias0 = ba[c0];
        const float bias1 = ba[c1];
        #pragma unroll
        for (int t = 0; t < 16; ++t) {
            int rloc = (t & 3) + 8 * (t >> 2) + 4 * lh;
            hid[rloc * K2P + c0] = f2bf(fmaxf(acc00[t] + bias0, 0.f));
            hid[rloc * K2P + c1] = f2bf(fmaxf(acc01[t] + bias1, 0.f));
        }
    }
    __syncthreads();

    // ---------------- stage 2 ----------------
    if (!LSM) {
        f32x16 d0 = {};
        const unsigned short* wfb = WfB + (size_t)wave * 16 * 512 + lane * 8;
        const int h0 = l31 * K2P + lh * 8;
        #pragma unroll
        for (int s = 0; s < 16; ++s) {
            s16x8 a0 = *(const s16x8*)&hid[h0 + s * 16];
            s16x8 b  = *(const s16x8*)(wfb + s * 512);
            d0 = __builtin_amdgcn_mfma_f32_32x32x16_bf16(a0, b, d0, 0, 0, 0);
        }
        const int col = wave * 32 + l31;
        const float bias = bb[col];
        #pragma unroll
        for (int t = 0; t < 16; ++t) {
            int rloc = (t & 3) + 8 * (t >> 2) + 4 * lh;
            int rr0 = row0 + rloc;
            if (rr0 < n)
                outq[(size_t)rr0 * 128 + col] = f2fp8(fmaxf(d0[t] + bias, 0.f));
        }
    } else {
        // waves 0,1 compute the 64 (padded) logit cols; waves 2,3 idle in MFMA
        float* lg = (float*)smem;           // [32][68] f32 = 8.7KB (after hid reads)
        f32x16 d = {};
        if (wave < 2) {
            const unsigned short* wfb = WfB + (size_t)wave * 16 * 512 + lane * 8;
            const int h0 = l31 * K2P + lh * 8;
            #pragma unroll
            for (int s = 0; s < 16; ++s) {
                s16x8 a = *(const s16x8*)&hid[h0 + s * 16];
                s16x8 b = *(const s16x8*)(wfb + s * 512);
                d = __builtin_amdgcn_mfma_f32_32x32x16_bf16(a, b, d, 0, 0, 0);
            }
        }
        __syncthreads();                    // done reading hid; reuse as logits
        if (wave < 2) {
            const int col = wave * 32 + l31;
            const float bias = (col < 40) ? bb[col] : 0.f;
            #pragma unroll
            for (int t = 0; t < 16; ++t) {
                int rloc = (t & 3) + 8 * (t >> 2) + 4 * lh;
                lg[rloc * 68 + col] = d[t] + bias;
            }
        }
        __syncthreads();
        const int r = tid >> 3, j = tid & 7;   // 8 threads/row, 5 cols each
        float mx = -1e30f;
        #pragma unroll
        for (int c = 0; c < 5; ++c) mx = fmaxf(mx, lg[r * 68 + j * 5 + c]);
        mx = fmaxf(mx, __shfl_xor(mx, 1));
        mx = fmaxf(mx, __shfl_xor(mx, 2));
        mx = fmaxf(mx, __shfl_xor(mx, 4));
        float sm = 0.f;
        #pragma unroll
        for (int c = 0; c < 5; ++c) sm += __expf(lg[r * 68 + j * 5 + c] - mx);
        sm += __shfl_xor(sm, 1);
        sm += __shfl_xor(sm, 2);
        sm += __shfl_xor(sm, 4);
        const float lse = mx + __logf(sm);
        const int row = row0 + r;
        float* out = (float*)outv;
        if (row < n) {
            #pragma unroll
            for (int c = 0; c < 5; ++c)
                out[(size_t)row * 40 + j * 5 + c] = lg[r * 68 + j * 5 + c] - lse;
        }
    }
}

// ===========================================================================
extern "C" void kernel_launch(void* const* d_in, const int* in_sizes, int n_in,
                              void* d_out, int out_size, void* d_ws, size_t ws_size,
                              hipStream_t stream) {
    const float* x   = (const float*)d_in[0];
    const int*   ei  = (const int*)d_in[1];
    const float* W1a = (const float*)d_in[2];
    const float* b1a = (const float*)d_in[3];
    const float* W1b = (const float*)d_in[4];
    const float* b1b = (const float*)d_in[5];
    const float* W2a = (const float*)d_in[6];
    const float* b2a = (const float*)d_in[7];
    const float* W2b = (const float*)d_in[8];
    const float* b2b = (const float*)d_in[9];
    const float* W3a = (const float*)d_in[10];
    const float* b3a = (const float*)d_in[11];
    const float* W3b = (const float*)d_in[12];
    const float* b3b = (const float*)d_in[13];
    float* out = (float*)d_out;

    const int E = in_sizes[1] / 2;
    const int N = in_sizes[0] / 48;
    const int* src = ei;
    const int* dst = ei + E;

    const int nprod = RNG;                      // 512 producers == 512 owners
    const int C     = (E + nprod - 1) / nprod;  // 3125 for E=1.6M (<= BMAX)
    const int per   = (N + RNG - 1) / RNG;      // 196 nodes/owner (<= 256)

    // ---- workspace carve-up (256B aligned) ----
    char* p = (char*)d_ws;
    auto alloc = [&](size_t bytes) { void* q = p; p += (bytes + 255) & ~(size_t)255; return q; };
    unsigned char*  xq   = (unsigned char*) alloc((size_t)N * 48);
    unsigned short* c1   = (unsigned short*)alloc((size_t)N * 48  * 2);
    unsigned char*  h1q  = (unsigned char*) alloc((size_t)N * 128);
    unsigned short* c2   = (unsigned short*)alloc((size_t)N * 128 * 2);  // also c3
    unsigned char*  h2q  = (unsigned char*) alloc((size_t)N * 128);
    unsigned short* Wf1a = (unsigned short*)alloc((size_t)24576 * 2);
    unsigned short* Wf1b = (unsigned short*)alloc((size_t)32768 * 2);
    unsigned short* Wf2a = (unsigned short*)alloc((size_t)77824 * 2);
    unsigned short* Wf2b = (unsigned short*)alloc((size_t)32768 * 2);
    unsigned short* Wf3a = (unsigned short*)alloc((size_t)77824 * 2);
    unsigned short* Wf3b = (unsigned short*)alloc((size_t)16384 * 2);
    int* deg     = (int*)alloc((size_t)N * 4);
    int* rowptr  = (int*)alloc((size_t)N * 4);
    int* csr_src = (int*)alloc((size_t)RNG * RCAP * 4);
    int2* pairs  = (int2*)alloc((size_t)nprod * C * 8);
    int* offsg   = (int*)alloc((size_t)nprod * (RNG + 1) * 4);

    const int nblk32 = (N + 31) / 32;

    // ---- merged prep + bucketize ----
    {
        int prep_total = N * 48 + WPREP;
        int nblk = RNG + (prep_total + 255) / 256;
        prep_bucketize<<<nblk, 256, 0, stream>>>(
            x, xq, W1a, Wf1a, W1b, Wf1b, W2a, Wf2a, W2b, Wf2b,
            W3a, Wf3a, W3b, Wf3b, src, dst, pairs, offsg, N, E, C, per);
    }
    place_all<<<RNG, 256, 0, stream>>>(pairs, offsg, rowptr, deg, csr_src,
                                       N, C, per);

    // ---- layer 1 ----
    lgconv_gather_fp8<48, 8, 8><<<((size_t)N * 8 + 255) / 256, 256, 0, stream>>>(
        xq, rowptr, deg, csr_src, c1, N);
    fused_mlp_mfma<48, 48, 0, false><<<nblk32, 256, 0, stream>>>(
        c1, xq, (const unsigned char*)nullptr, Wf1a, b1a, Wf1b, b1b,
        nullptr, h1q, N);

    // ---- layer 2 ----
    lgconv_gather_fp8<128, 8, 16><<<((size_t)N * 8 + 255) / 256, 256, 0, stream>>>(
        h1q, rowptr, deg, csr_src, c2, N);
    fused_mlp_mfma<128, 128, 48, false><<<nblk32, 256, 0, stream>>>(
        c2, h1q, xq, Wf2a, b2a, Wf2b, b2b, nullptr, h2q, N);

    // ---- layer 3 ----
    lgconv_gather_fp8<128, 8, 16><<<((size_t)N * 8 + 255) / 256, 256, 0, stream>>>(
        h2q, rowptr, deg, csr_src, c2, N);   // c3 reuses c2 slot
    fused_mlp_mfma<128, 128, 48, true><<<nblk32, 256, 0, stream>>>(
        c2, h2q, xq, Wf3a, b3a, Wf3b, b3b, out, (unsigned char*)nullptr, N);
}

// Round 14
// 324.273 us; speedup vs baseline: 1.0747x; 1.0236x over previous
//
#include <hip/hip_runtime.h>
#include <math.h>

typedef __attribute__((ext_vector_type(8)))  short s16x8;   // 8 bf16 (4 VGPRs)
typedef __attribute__((ext_vector_type(16))) float f32x16;  // MFMA 32x32 acc
typedef __attribute__((ext_vector_type(2)))  float f32x2;

__device__ inline unsigned short f2bf(float f) {           // RNE f32 -> bf16
    unsigned u = __float_as_uint(f);
    u += 0x7fffu + ((u >> 16) & 1u);
    return (unsigned short)(u >> 16);
}
__device__ inline unsigned char f2fp8(float v) {           // f32 -> fp8 e4m3 (OCP on gfx950)
    return (unsigned char)(__builtin_amdgcn_cvt_pk_fp8_f32(v, v, 0, false) & 0xff);
}
// accumulate 8 fp8 channels (uint2) into f32 acc via HW cvt
__device__ inline void acc_fp8x8(float* a, uint2 v) {
    f32x2 p0 = __builtin_amdgcn_cvt_pk_f32_fp8(v.x, false);
    f32x2 p1 = __builtin_amdgcn_cvt_pk_f32_fp8(v.x, true);
    f32x2 p2 = __builtin_amdgcn_cvt_pk_f32_fp8(v.y, false);
    f32x2 p3 = __builtin_amdgcn_cvt_pk_f32_fp8(v.y, true);
    a[0] += p0.x; a[1] += p0.y; a[2] += p1.x; a[3] += p1.y;
    a[4] += p2.x; a[5] += p2.y; a[6] += p3.x; a[7] += p3.y;
}
// 8 fp8 -> 8 bf16 packed (EXACT: e4m3 values are representable in bf16)
__device__ inline uint4 fp8x8_to_bf16x8(uint2 v) {
    f32x2 p0 = __builtin_amdgcn_cvt_pk_f32_fp8(v.x, false);
    f32x2 p1 = __builtin_amdgcn_cvt_pk_f32_fp8(v.x, true);
    f32x2 p2 = __builtin_amdgcn_cvt_pk_f32_fp8(v.y, false);
    f32x2 p3 = __builtin_amdgcn_cvt_pk_f32_fp8(v.y, true);
    uint4 o;
    o.x = ((unsigned)f2bf(p0.y) << 16) | f2bf(p0.x);
    o.y = ((unsigned)f2bf(p1.y) << 16) | f2bf(p1.x);
    o.z = ((unsigned)f2bf(p2.y) << 16) | f2bf(p2.x);
    o.w = ((unsigned)f2bf(p3.y) << 16) | f2bf(p3.x);
    return o;
}
__device__ inline uint4 pack_bf16x8(const float* a) {
    uint4 o;
    o.x = ((unsigned)f2bf(a[1]) << 16) | f2bf(a[0]);
    o.y = ((unsigned)f2bf(a[3]) << 16) | f2bf(a[2]);
    o.z = ((unsigned)f2bf(a[5]) << 16) | f2bf(a[4]);
    o.w = ((unsigned)f2bf(a[7]) << 16) | f2bf(a[6]);
    return o;
}

#define BMAX 3200   // max edges per producer chunk (LDS-resident)
#define RNG  512    // owner ranges (= producer count); per-range nodes <= 256
#define WPREP 262144 // total weight-permute elements
#define RCAP 4096   // fixed csr_src capacity per range (mean 3125, sd 56 -> >17 sd)

// ===========================================================================
// Merged prep + bucketize: blocks [0,RNG) bucketize; blocks >= RNG run prep.
// ===========================================================================
__global__ __launch_bounds__(256)
void prep_bucketize(const float* __restrict__ x, unsigned char* __restrict__ xq,
                    const float* __restrict__ W1a, unsigned short* __restrict__ Wf1a,
                    const float* __restrict__ W1b, unsigned short* __restrict__ Wf1b,
                    const float* __restrict__ W2a, unsigned short* __restrict__ Wf2a,
                    const float* __restrict__ W2b, unsigned short* __restrict__ Wf2b,
                    const float* __restrict__ W3a, unsigned short* __restrict__ Wf3a,
                    const float* __restrict__ W3b, unsigned short* __restrict__ Wf3b,
                    const int* __restrict__ src, const int* __restrict__ dst,
                    int2* __restrict__ pairs, int* __restrict__ offsg,
                    int N, int E, int C, int per) {
    __shared__ int sdst[BMAX];
    __shared__ int ssrc[BMAX];
    __shared__ int cnt[RNG];
    __shared__ int cur[RNG + 1];
    __shared__ int sh[256];
    const int t = threadIdx.x;

    if (blockIdx.x < RNG) {
        // ---------------- bucketize path ----------------
        const int p    = blockIdx.x;
        const int base = p * C;
        const int len  = min(C, E - base);

        cnt[t] = 0; cnt[t + 256] = 0;
        for (int i = t; i < len; i += 256) { sdst[i] = dst[base + i]; ssrc[i] = src[base + i]; }
        __syncthreads();
        for (int i = t; i < len; i += 256) {
            int r = sdst[i] / per;
            atomicAdd(&cnt[r], 1);
        }
        __syncthreads();
        const int cA = cnt[2 * t], cB = cnt[2 * t + 1];
        sh[t] = cA + cB;
        __syncthreads();
        for (int off = 1; off < 256; off <<= 1) {
            int add = (t >= off) ? sh[t - off] : 0;
            __syncthreads();
            sh[t] += add;
            __syncthreads();
        }
        const int excl = sh[t] - cA - cB;
        cur[2 * t] = excl;
        cur[2 * t + 1] = excl + cA;
        if (t == 255) cur[RNG] = sh[255];
        offsg[p * (RNG + 1) + 2 * t]     = excl;
        offsg[p * (RNG + 1) + 2 * t + 1] = excl + cA;
        if (t == 255) offsg[p * (RNG + 1) + RNG] = sh[255];
        __syncthreads();
        for (int i = t; i < len; i += 256) {
            int d = sdst[i];
            int r = d / per;
            int pos = atomicAdd(&cur[r], 1);
            pairs[base + pos] = make_int2(ssrc[i], d);
        }
        return;
    }

    // ---------------- prep path ----------------
    int i = (blockIdx.x - RNG) * 256 + t;
    int nx = N * 48;
    if (i < nx) { xq[i] = f2fp8(x[i]); return; }
    i -= nx;
    if (i < 24576) {   // Wf1a: K1=96, NS1=6
        int j = i & 7, lane = (i >> 3) & 63, pp = (i >> 9) & 1, sw = i >> 10;
        int s = sw % 6, w = sw / 6;
        int col = w * 64 + pp * 32 + (lane & 31);
        int k   = s * 16 + (lane >> 5) * 8 + j;
        Wf1a[i] = f2bf(W1a[(size_t)k * 256 + col]); return;
    }
    i -= 24576;
    if (i < 32768) {   // Wf1b: [256][128]
        int j = i & 7, lane = (i >> 3) & 63, sw = i >> 9;
        int s = sw & 15, w = sw >> 4;
        int col = w * 32 + (lane & 31);
        int k   = s * 16 + (lane >> 5) * 8 + j;
        Wf1b[i] = f2bf(W1b[(size_t)k * 128 + col]); return;
    }
    i -= 32768;
    if (i < 77824) {   // Wf2a: K1=304, NS1=19
        int j = i & 7, lane = (i >> 3) & 63, pp = (i >> 9) & 1, sw = i >> 10;
        int s = sw % 19, w = sw / 19;
        int col = w * 64 + pp * 32 + (lane & 31);
        int k   = s * 16 + (lane >> 5) * 8 + j;
        Wf2a[i] = f2bf(W2a[(size_t)k * 256 + col]); return;
    }
    i -= 77824;
    if (i < 32768) {   // Wf2b: [256][128]
        int j = i & 7, lane = (i >> 3) & 63, sw = i >> 9;
        int s = sw & 15, w = sw >> 4;
        int col = w * 32 + (lane & 31);
        int k   = s * 16 + (lane >> 5) * 8 + j;
        Wf2b[i] = f2bf(W2b[(size_t)k * 128 + col]); return;
    }
    i -= 32768;
    if (i < 77824) {   // Wf3a: K1=304, NS1=19
        int j = i & 7, lane = (i >> 3) & 63, pp = (i >> 9) & 1, sw = i >> 10;
        int s = sw % 19, w = sw / 19;
        int col = w * 64 + pp * 32 + (lane & 31);
        int k   = s * 16 + (lane >> 5) * 8 + j;
        Wf3a[i] = f2bf(W3a[(size_t)k * 256 + col]); return;
    }
    i -= 77824;
    if (i < 16384) {   // Wf3b: [256][40->64 pad], 2 wave-groups (ct)
        int j = i & 7, lane = (i >> 3) & 63, sw = i >> 9;
        int s = sw & 15, w = sw >> 4;      // w in {0,1}
        int col = w * 32 + (lane & 31);
        int k   = s * 16 + (lane >> 5) * 8 + j;
        float v = (col < 40) ? W3b[(size_t)k * 40 + col] : 0.f;
        Wf3b[i] = f2bf(v); return;
    }
}

// ===========================================================================
// place_all with FIXED per-range base rb = r*RCAP (kept: removes range_tot).
// ===========================================================================
__global__ __launch_bounds__(256)
void place_all(const int2* __restrict__ pairs, const int* __restrict__ offsg,
               int* __restrict__ rowptr, int* __restrict__ deg,
               int* __restrict__ csr_src, int N, int C, int per) {
    __shared__ int po[RNG];
    __shared__ int W[RNG + 1];
    __shared__ int sh[256];
    __shared__ int dcnt[256];
    __shared__ int curs[256];
    const int r  = blockIdx.x;
    const int lo = r * per;
    const int hi = min(lo + per, N);
    const int cnt = hi - lo;
    if (cnt <= 0) return;
    const int t = threadIdx.x;
    const int rb = r * RCAP;

    dcnt[t] = 0;
    const int pA = 2 * t, pB = 2 * t + 1;
    const int oA0 = offsg[pA * (RNG + 1) + r];
    const int oA1 = offsg[pA * (RNG + 1) + r + 1];
    const int oB0 = offsg[pB * (RNG + 1) + r];
    const int oB1 = offsg[pB * (RNG + 1) + r + 1];
    po[pA] = oA0; po[pB] = oB0;
    const int cA = oA1 - oA0, cB = oB1 - oB0;
    sh[t] = cA + cB;
    __syncthreads();
    for (int off = 1; off < 256; off <<= 1) {
        int add = (t >= off) ? sh[t - off] : 0;
        __syncthreads();
        sh[t] += add;
        __syncthreads();
    }
    const int excl = sh[t] - cA - cB;
    W[pA] = excl; W[pB] = excl + cA;
    if (t == 255) W[RNG] = sh[255];
    __syncthreads();
    const int tot = W[RNG];
    // pass 1: per-node counts
    for (int i = t; i < tot; i += 256) {
        int a = 0, b = RNG;
        while (b - a > 1) { int m = (a + b) >> 1; if (W[m] <= i) a = m; else b = m; }
        const int2 pr = pairs[(size_t)a * C + po[a] + (i - W[a])];
        atomicAdd(&dcnt[pr.y - lo], 1);
    }
    __syncthreads();
    // LDS exclusive scan of dcnt
    const int myc = dcnt[t];
    sh[t] = myc;
    __syncthreads();
    for (int off = 1; off < 256; off <<= 1) {
        int add = (t >= off) ? sh[t - off] : 0;
        __syncthreads();
        sh[t] += add;
        __syncthreads();
    }
    const int loc = sh[t] - myc;
    if (t < cnt) { rowptr[lo + t] = rb + loc; deg[lo + t] = myc; }
    curs[t] = rb + loc;
    __syncthreads();
    // pass 2: place (same pairs bytes, L2-hot)
    for (int i = t; i < tot; i += 256) {
        int a = 0, b = RNG;
        while (b - a > 1) { int m = (a + b) >> 1; if (W[m] <= i) a = m; else b = m; }
        const int2 pr = pairs[(size_t)a * C + po[a] + (i - W[a])];
        const int pos = atomicAdd(&curs[pr.y - lo], 1);   // LDS atomic
        if (pos < RNG * RCAP) csr_src[pos] = pr.x;
    }
}

// ===========================================================================
// LGConv gather from FP8 table — proven round-10/11 form (best measured):
// LPN lanes/node, 8B uint2 loads, int4 index loads, 8-edge unroll.
// (Round-13's LPN8/CPL16 variant reverted: fewer wider loads lost ~5us —
// the gather is at the compulsory L2-fill floor, not issue-bound.)
// ===========================================================================
template<int D, int LPN>
__global__ __launch_bounds__(256)
void lgconv_gather_fp8(const unsigned char* __restrict__ xq,
                       const int* __restrict__ rowptr,
                       const int* __restrict__ deg,
                       const int* __restrict__ csr_src,
                       unsigned short* __restrict__ out, int N) {
    const int g    = (blockIdx.x * 256 + threadIdx.x) / LPN;
    const int lane = threadIdx.x & (LPN - 1);
    if (g >= N) return;
    if (lane * 8 >= D) return;
    const int start = rowptr[g];
    const int dg    = deg[g];
    const unsigned char* xb = xq + lane * 8;
    float acc[8] = {0.f,0.f,0.f,0.f,0.f,0.f,0.f,0.f};
    int j = 0;
    for (; j + 7 < dg; j += 8) {
        const int4 ia = *(const int4*)(csr_src + start + j);
        const int4 ib = *(const int4*)(csr_src + start + j + 4);
        uint2 v0 = *(const uint2*)(xb + (size_t)ia.x * D);
        uint2 v1 = *(const uint2*)(xb + (size_t)ia.y * D);
        uint2 v2 = *(const uint2*)(xb + (size_t)ia.z * D);
        uint2 v3 = *(const uint2*)(xb + (size_t)ia.w * D);
        uint2 v4 = *(const uint2*)(xb + (size_t)ib.x * D);
        uint2 v5 = *(const uint2*)(xb + (size_t)ib.y * D);
        uint2 v6 = *(const uint2*)(xb + (size_t)ib.z * D);
        uint2 v7 = *(const uint2*)(xb + (size_t)ib.w * D);
        acc_fp8x8(acc, v0); acc_fp8x8(acc, v1);
        acc_fp8x8(acc, v2); acc_fp8x8(acc, v3);
        acc_fp8x8(acc, v4); acc_fp8x8(acc, v5);
        acc_fp8x8(acc, v6); acc_fp8x8(acc, v7);
    }
    if (j + 3 < dg) {
        const int4 ia = *(const int4*)(csr_src + start + j);
        uint2 v0 = *(const uint2*)(xb + (size_t)ia.x * D);
        uint2 v1 = *(const uint2*)(xb + (size_t)ia.y * D);
        uint2 v2 = *(const uint2*)(xb + (size_t)ia.z * D);
        uint2 v3 = *(const uint2*)(xb + (size_t)ia.w * D);
        acc_fp8x8(acc, v0); acc_fp8x8(acc, v1);
        acc_fp8x8(acc, v2); acc_fp8x8(acc, v3);
        j += 4;
    }
    for (; j < dg; ++j) {
        const int s0 = csr_src[start + j];
        uint2 v0 = *(const uint2*)(xb + (size_t)s0 * D);
        acc_fp8x8(acc, v0);
    }
    uint4 o = pack_bf16x8(acc);
    *(uint4*)(out + (size_t)g * D + lane * 8) = o;
}

// ===========================================================================
// Fused 2-layer MLP, bf16 MFMA (32x32x16), 32 rows/block, 4 waves.
// EXACT round-11 form. Rounds 5-12 proved this ~41us schedule is the floor
// for this structure. DO NOT TOUCH.
// ===========================================================================
template<int LA, int LB, int LC, bool LSM>
__global__ __launch_bounds__(256)
void fused_mlp_mfma(const unsigned short* __restrict__ segA,
                    const unsigned char* __restrict__ segB,
                    const unsigned char* __restrict__ segC,
                    const unsigned short* __restrict__ WfA, const float* __restrict__ ba,
                    const unsigned short* __restrict__ WfB, const float* __restrict__ bb,
                    void* __restrict__ outv, unsigned char* __restrict__ outq,
                    int n) {
    constexpr int K1   = LA + LB + LC;      // 96 or 304
    constexpr int NS1  = K1 / 16;
    constexpr int NCH  = K1 / 8;            // 16B chunks per row
    constexpr int KPAD = K1 + 8;            // 104 or 312 (16B-aligned rows)
    constexpr int K2P  = 264;               // hid row stride (bf16)
    constexpr int SW   = (32 * KPAD > 32 * K2P) ? 32 * KPAD : 32 * K2P;
    __shared__ __attribute__((aligned(16))) unsigned short smem[SW];
    unsigned short* Ab  = smem;             // stage-1 A tile   [32][KPAD]
    unsigned short* hid = smem;             // stage-1 out      [32][K2P] (union)

    const int tid  = threadIdx.x;
    const int wave = tid >> 6;
    const int lane = tid & 63;
    const int l31  = lane & 31;
    const int lh   = lane >> 5;
    const int row0 = blockIdx.x * 32;

    // ---- stage A tile: segA bf16 direct; segB/segC fp8 -> bf16 convert ----
    for (int c = tid; c < 32 * NCH; c += 256) {
        const int m  = c / NCH;
        const int kc = c - m * NCH;
        const int row = row0 + m;
        const int ra  = (row < n) ? row : (n - 1);
        uint4 val;
        if (kc * 8 < LA) {
            val = *(const uint4*)(segA + (size_t)ra * LA + kc * 8);
        } else {
            const unsigned char* qp;
            int koff;
            if (kc * 8 < LA + LB) { qp = segB + (size_t)ra * LB; koff = kc * 8 - LA; }
            else                  { qp = segC + (size_t)ra * LC; koff = kc * 8 - LA - LB; }
            val = fp8x8_to_bf16x8(*(const uint2*)(qp + koff));
        }
        *(uint4*)(Ab + m * KPAD + kc * 8) = val;
    }
    __syncthreads();

    // ---------------- stage 1: rows 0-31, 64 cols/wave ----------------
    f32x16 acc00 = {}, acc01 = {};
    const unsigned short* wfa = WfA + (size_t)wave * NS1 * 1024 + lane * 8;
    const int a0off = l31 * KPAD + lh * 8;

    #pragma unroll
    for (int s = 0; s < NS1; ++s) {
        s16x8 a0 = *(const s16x8*)(Ab + a0off + s * 16);
        s16x8 b0 = *(const s16x8*)(wfa + s * 1024);
        s16x8 b1 = *(const s16x8*)(wfa + s * 1024 + 512);
        acc00 = __builtin_amdgcn_mfma_f32_32x32x16_bf16(a0, b0, acc00, 0, 0, 0);
        acc01 = __builtin_amdgcn_mfma_f32_32x32x16_bf16(a0, b1, acc01, 0, 0, 0);
    }
    __syncthreads();                        // all A reads done before hid overwrites

    // epilogue: + bias, relu -> hid[m][k] bf16 (C/D layout, m74/m101)
    {
        const int c0 = wave * 64 + l31;
        const int c1 = c0 + 32;
        const float bias0 = ba[c0];
        const float bias1 = ba[c1];
        #pragma unroll
        for (int t = 0; t < 16; ++t) {
            int rloc = (t & 3) + 8 * (t >> 2) + 4 * lh;
            hid[rloc * K2P + c0] = f2bf(fmaxf(acc00[t] + bias0, 0.f));
            hid[rloc * K2P + c1] = f2bf(fmaxf(acc01[t] + bias1, 0.f));
        }
    }
    __syncthreads();

    // ---------------- stage 2 ----------------
    if (!LSM) {
        f32x16 d0 = {};
        const unsigned short* wfb = WfB + (size_t)wave * 16 * 512 + lane * 8;
        const int h0 = l31 * K2P + lh * 8;
        #pragma unroll
        for (int s = 0; s < 16; ++s) {
            s16x8 a0 = *(const s16x8*)&hid[h0 + s * 16];
            s16x8 b  = *(const s16x8*)(wfb + s * 512);
            d0 = __builtin_amdgcn_mfma_f32_32x32x16_bf16(a0, b, d0, 0, 0, 0);
        }
        const int col = wave * 32 + l31;
        const float bias = bb[col];
        #pragma unroll
        for (int t = 0; t < 16; ++t) {
            int rloc = (t & 3) + 8 * (t >> 2) + 4 * lh;
            int rr0 = row0 + rloc;
            if (rr0 < n)
                outq[(size_t)rr0 * 128 + col] = f2fp8(fmaxf(d0[t] + bias, 0.f));
        }
    } else {
        // waves 0,1 compute the 64 (padded) logit cols; waves 2,3 idle in MFMA
        float* lg = (float*)smem;           // [32][68] f32 = 8.7KB (after hid reads)
        f32x16 d = {};
        if (wave < 2) {
            const unsigned short* wfb = WfB + (size_t)wave * 16 * 512 + lane * 8;
            const int h0 = l31 * K2P + lh * 8;
            #pragma unroll
            for (int s = 0; s < 16; ++s) {
                s16x8 a = *(const s16x8*)&hid[h0 + s * 16];
                s16x8 b = *(const s16x8*)(wfb + s * 512);
                d = __builtin_amdgcn_mfma_f32_32x32x16_bf16(a, b, d, 0, 0, 0);
            }
        }
        __syncthreads();                    // done reading hid; reuse as logits
        if (wave < 2) {
            const int col = wave * 32 + l31;
            const float bias = (col < 40) ? bb[col] : 0.f;
            #pragma unroll
            for (int t = 0; t < 16; ++t) {
                int rloc = (t & 3) + 8 * (t >> 2) + 4 * lh;
                lg[rloc * 68 + col] = d[t] + bias;
            }
        }
        __syncthreads();
        const int r = tid >> 3, j = tid & 7;   // 8 threads/row, 5 cols each
        float mx = -1e30f;
        #pragma unroll
        for (int c = 0; c < 5; ++c) mx = fmaxf(mx, lg[r * 68 + j * 5 + c]);
        mx = fmaxf(mx, __shfl_xor(mx, 1));
        mx = fmaxf(mx, __shfl_xor(mx, 2));
        mx = fmaxf(mx, __shfl_xor(mx, 4));
        float sm = 0.f;
        #pragma unroll
        for (int c = 0; c < 5; ++c) sm += __expf(lg[r * 68 + j * 5 + c] - mx);
        sm += __shfl_xor(sm, 1);
        sm += __shfl_xor(sm, 2);
        sm += __shfl_xor(sm, 4);
        const float lse = mx + __logf(sm);
        const int row = row0 + r;
        float* out = (float*)outv;
        if (row < n) {
            #pragma unroll
            for (int c = 0; c < 5; ++c)
                out[(size_t)row * 40 + j * 5 + c] = lg[r * 68 + j * 5 + c] - lse;
        }
    }
}

// ===========================================================================
extern "C" void kernel_launch(void* const* d_in, const int* in_sizes, int n_in,
                              void* d_out, int out_size, void* d_ws, size_t ws_size,
                              hipStream_t stream) {
    const float* x   = (const float*)d_in[0];
    const int*   ei  = (const int*)d_in[1];
    const float* W1a = (const float*)d_in[2];
    const float* b1a = (const float*)d_in[3];
    const float* W1b = (const float*)d_in[4];
    const float* b1b = (const float*)d_in[5];
    const float* W2a = (const float*)d_in[6];
    const float* b2a = (const float*)d_in[7];
    const float* W2b = (const float*)d_in[8];
    const float* b2b = (const float*)d_in[9];
    const float* W3a = (const float*)d_in[10];
    const float* b3a = (const float*)d_in[11];
    const float* W3b = (const float*)d_in[12];
    const float* b3b = (const float*)d_in[13];
    float* out = (float*)d_out;

    const int E = in_sizes[1] / 2;
    const int N = in_sizes[0] / 48;
    const int* src = ei;
    const int* dst = ei + E;

    const int nprod = RNG;                      // 512 producers == 512 owners
    const int C     = (E + nprod - 1) / nprod;  // 3125 for E=1.6M (<= BMAX)
    const int per   = (N + RNG - 1) / RNG;      // 196 nodes/owner (<= 256)

    // ---- workspace carve-up (256B aligned) ----
    char* p = (char*)d_ws;
    auto alloc = [&](size_t bytes) { void* q = p; p += (bytes + 255) & ~(size_t)255; return q; };
    unsigned char*  xq   = (unsigned char*) alloc((size_t)N * 48);
    unsigned short* c1   = (unsigned short*)alloc((size_t)N * 48  * 2);
    unsigned char*  h1q  = (unsigned char*) alloc((size_t)N * 128);
    unsigned short* c2   = (unsigned short*)alloc((size_t)N * 128 * 2);  // also c3
    unsigned char*  h2q  = (unsigned char*) alloc((size_t)N * 128);
    unsigned short* Wf1a = (unsigned short*)alloc((size_t)24576 * 2);
    unsigned short* Wf1b = (unsigned short*)alloc((size_t)32768 * 2);
    unsigned short* Wf2a = (unsigned short*)alloc((size_t)77824 * 2);
    unsigned short* Wf2b = (unsigned short*)alloc((size_t)32768 * 2);
    unsigned short* Wf3a = (unsigned short*)alloc((size_t)77824 * 2);
    unsigned short* Wf3b = (unsigned short*)alloc((size_t)16384 * 2);
    int* deg     = (int*)alloc((size_t)N * 4);
    int* rowptr  = (int*)alloc((size_t)N * 4);
    int* csr_src = (int*)alloc((size_t)RNG * RCAP * 4);
    int2* pairs  = (int2*)alloc((size_t)nprod * C * 8);
    int* offsg   = (int*)alloc((size_t)nprod * (RNG + 1) * 4);

    const int nblk32 = (N + 31) / 32;

    // ---- merged prep + bucketize ----
    {
        int prep_total = N * 48 + WPREP;
        int nblk = RNG + (prep_total + 255) / 256;
        prep_bucketize<<<nblk, 256, 0, stream>>>(
            x, xq, W1a, Wf1a, W1b, Wf1b, W2a, Wf2a, W2b, Wf2b,
            W3a, Wf3a, W3b, Wf3b, src, dst, pairs, offsg, N, E, C, per);
    }
    place_all<<<RNG, 256, 0, stream>>>(pairs, offsg, rowptr, deg, csr_src,
                                       N, C, per);

    // ---- layer 1 ----
    lgconv_gather_fp8<48, 8><<<((size_t)N * 8 + 255) / 256, 256, 0, stream>>>(
        xq, rowptr, deg, csr_src, c1, N);
    fused_mlp_mfma<48, 48, 0, false><<<nblk32, 256, 0, stream>>>(
        c1, xq, (const unsigned char*)nullptr, Wf1a, b1a, Wf1b, b1b,
        nullptr, h1q, N);

    // ---- layer 2 ----
    lgconv_gather_fp8<128, 16><<<((size_t)N * 16 + 255) / 256, 256, 0, stream>>>(
        h1q, rowptr, deg, csr_src, c2, N);
    fused_mlp_mfma<128, 128, 48, false><<<nblk32, 256, 0, stream>>>(
        c2, h1q, xq, Wf2a, b2a, Wf2b, b2b, nullptr, h2q, N);

    // ---- layer 3 ----
    lgconv_gather_fp8<128, 16><<<((size_t)N * 16 + 255) / 256, 256, 0, stream>>>(
        h2q, rowptr, deg, csr_src, c2, N);   // c3 reuses c2 slot
    fused_mlp_mfma<128, 128, 48, true><<<nblk32, 256, 0, stream>>>(
        c2, h2q, xq, Wf3a, b3a, Wf3b, b3b, out, (unsigned char*)nullptr, N);
}